// Round 17
// baseline (486.115 us; speedup 1.0000x reference)
//
#include <hip/hip_runtime.h>

typedef _Float16 f16;
typedef _Float16 f16x4 __attribute__((ext_vector_type(4)));
typedef _Float16 f16x8 __attribute__((ext_vector_type(8)));
typedef float f32x4 __attribute__((ext_vector_type(4)));

#define MFMA16(a, b, c) __builtin_amdgcn_mfma_f32_16x16x32_f16((a), (b), (c), 0, 0, 0)

__device__ __forceinline__ void gload16(const void* g, void* l) {
  __builtin_amdgcn_global_load_lds(
      (const __attribute__((address_space(1))) void*)g,
      (__attribute__((address_space(3))) void*)l, 16, 0, 0);
}

// swizzled LDS fragment read: buf is [rows][64] f16 linear, ch in 0..7 (16B chunks)
__device__ __forceinline__ f16x8 lds8(const f16* buf, int row, int ch) {
  return *(const f16x8*)(buf + row * 64 + ((ch ^ (row & 7)) << 3));
}

// BK=32 variant: buf is [rows][32] f16 linear, hi in 0..3 (16B chunks)
__device__ __forceinline__ f16x8 lds32(const f16* buf, int row, int hi) {
  return *(const f16x8*)(buf + row * 32 + ((hi ^ ((row >> 1) & 3)) << 3));
}

#define VMW4 asm volatile("s_waitcnt vmcnt(4)" ::: "memory")
#define VMW0 asm volatile("s_waitcnt vmcnt(0)" ::: "memory")
#define BAR __builtin_amdgcn_s_barrier()

// Sizes: B=64, N=1024, C=512, H=8, D=64, M=64, BH=512. SCALE=0.125f.

// ---------------- K1: fused prep: x->f16 + pooling (bid<512), weights (else) ----------------
__global__ __launch_bounds__(256) void k_prep(
    const float* __restrict__ x, const float* __restrict__ Wq,
    const float* __restrict__ Wkv, const float* __restrict__ Wp,
    const float* __restrict__ bq, const float* __restrict__ bkv,
    f16* __restrict__ xh, float* __restrict__ xm, f16* __restrict__ WcT,
    f16* __restrict__ WpT, float* __restrict__ bc,
    unsigned* __restrict__ den) {
  __shared__ float pl[4][8][512];
  int bid = blockIdx.x;
  int tid = threadIdx.x;
  if (bid >= 512) {
    int b = bid - 512;
    if (b < 1536) {
      for (int kk = tid; kk < 512; kk += 256) {
        float w = (b < 512) ? Wq[kk * 512 + b] : Wkv[kk * 1024 + (b - 512)];
        WcT[b * 512 + kk] = (f16)w;
      }
      if (tid == 0) bc[b] = (b < 512) ? bq[b] : bkv[b - 512];
      if (b == 0 && tid == 1) { den[0] = 0u; den[1] = 0u; }
    } else {
      int pc = b - 1536;
      for (int kk = tid; kk < 512; kk += 256)
        WpT[pc * 512 + kk] = (f16)Wp[kk * 512 + pc];
    }
    return;
  }
  int b = bid >> 3, a = bid & 7;
  int tr = tid >> 6, cl = tid & 63;
  int c0 = cl * 8;
  float pacc[8][8];
#pragma unroll
  for (int i = 0; i < 8; i++)
#pragma unroll
    for (int j = 0; j < 8; j++) pacc[i][j] = 0.f;
#pragma unroll
  for (int j = 0; j < 32; j++) {
    int n = a * 128 + tr * 32 + j;
    const float* row = x + (size_t)(b * 1024 + n) * 512 + c0;
    float4 v0 = *(const float4*)row;
    float4 v1 = *(const float4*)(row + 4);
    f16x8 h;
    h[0] = (f16)v0.x; h[1] = (f16)v0.y; h[2] = (f16)v0.z; h[3] = (f16)v0.w;
    h[4] = (f16)v1.x; h[5] = (f16)v1.y; h[6] = (f16)v1.z; h[7] = (f16)v1.w;
    *(f16x8*)(xh + (size_t)(b * 1024 + n) * 512 + c0) = h;
    int cg = j >> 2;
    pacc[cg][0] += v0.x; pacc[cg][1] += v0.y; pacc[cg][2] += v0.z;
    pacc[cg][3] += v0.w; pacc[cg][4] += v1.x; pacc[cg][5] += v1.y;
    pacc[cg][6] += v1.z; pacc[cg][7] += v1.w;
  }
#pragma unroll
  for (int cg = 0; cg < 8; cg++) {
    *(float4*)&pl[tr][cg][c0] =
        make_float4(pacc[cg][0], pacc[cg][1], pacc[cg][2], pacc[cg][3]);
    *(float4*)&pl[tr][cg][c0 + 4] =
        make_float4(pacc[cg][4], pacc[cg][5], pacc[cg][6], pacc[cg][7]);
  }
  __syncthreads();
#pragma unroll
  for (int s = 0; s < 4; s++) {
    int o = tid + s * 256;
    int cg = o >> 7, c4 = (o & 127) << 2;
    float4 r0 = *(const float4*)&pl[0][cg][c4];
    float4 r1 = *(const float4*)&pl[1][cg][c4];
    float4 r2 = *(const float4*)&pl[2][cg][c4];
    float4 r3 = *(const float4*)&pl[3][cg][c4];
    float4 r;
    r.x = (r0.x + r1.x + r2.x + r3.x) * 0.0625f;
    r.y = (r0.y + r1.y + r2.y + r3.y) * 0.0625f;
    r.z = (r0.z + r1.z + r2.z + r3.z) * 0.0625f;
    r.w = (r0.w + r1.w + r2.w + r3.w) * 0.0625f;
    *(float4*)(xm + (size_t)(b * 64 + a * 8 + cg) * 512 + c4) = r;
  }
}

// ---------------- K3: QKV GEMM 256x256, BK=32, 64KB dbuf LDS, 2 blocks/CU ----------------
__global__ __launch_bounds__(512) void k_qkv(
    const f16* __restrict__ xh, const f16* __restrict__ WcT,
    const float* __restrict__ bc, f16* __restrict__ qb, f16* __restrict__ kb,
    f16* __restrict__ vb) {
  __shared__ f16 Al[2][256 * 32];
  __shared__ f16 Bl[2][256 * 32];
  int bid = blockIdx.x;
  int swz = (bid & 7) * 192 + (bid >> 3);   // nwg=1536, bijective
  int ct = swz % 6, rt = swz / 6;
  int m0 = rt * 256, n0 = ct * 256;
  int tid = threadIdx.x, lane = tid & 63, w = tid >> 6;
  int lr = lane & 15, hi = lane >> 4;
  int wr = w >> 2, wc = w & 3;              // 2x4 wave grid; wave owns 128x64

  int srow = tid >> 2;                      // 0..127; second load covers +128
  int cg = (tid & 3) ^ ((srow >> 1) & 3);   // pre-swizzled global chunk
  const f16* gA = xh + (size_t)(m0 + srow) * 512 + cg * 8;
  const f16* gB = WcT + (size_t)(n0 + srow) * 512 + cg * 8;

  f32x4 acc[4][8] = {};   // [ni][mi], swapped operands

#define STG(BUF, K0)                                              \
  {                                                               \
    gload16(gA + (K0), &Al[BUF][tid * 8]);                        \
    gload16(gA + (K0) + 128 * 512, &Al[BUF][tid * 8 + 4096]);     \
    gload16(gB + (K0), &Bl[BUF][tid * 8]);                        \
    gload16(gB + (K0) + 128 * 512, &Bl[BUF][tid * 8 + 4096]);     \
  }
#define CMP(BUF)                                                  \
  {                                                               \
    __builtin_amdgcn_s_setprio(1);                                \
    f16x8 af[4], bf[8];                                           \
    _Pragma("unroll") for (int ni = 0; ni < 4; ni++)              \
        af[ni] = lds32(&Bl[BUF][0], wc * 64 + ni * 16 + lr, hi);  \
    _Pragma("unroll") for (int mi = 0; mi < 8; mi++)              \
        bf[mi] = lds32(&Al[BUF][0], wr * 128 + mi * 16 + lr, hi); \
    _Pragma("unroll") for (int ni = 0; ni < 4; ni++)              \
        _Pragma("unroll") for (int mi = 0; mi < 8; mi++)          \
            acc[ni][mi] = MFMA16(af[ni], bf[mi], acc[ni][mi]);    \
    __builtin_amdgcn_s_setprio(0);                                \
  }

  STG(0, 0);
  STG(1, 32);
  VMW4; BAR; CMP(0); BAR; STG(0, 2 * 32);
  VMW4; BAR; CMP(1); BAR; STG(1, 3 * 32);
  VMW4; BAR; CMP(0); BAR; STG(0, 4 * 32);
  VMW4; BAR; CMP(1); BAR; STG(1, 5 * 32);
  VMW4; BAR; CMP(0); BAR; STG(0, 6 * 32);
  VMW4; BAR; CMP(1); BAR; STG(1, 7 * 32);
  VMW4; BAR; CMP(0); BAR; STG(0, 8 * 32);
  VMW4; BAR; CMP(1); BAR; STG(1, 9 * 32);
  VMW4; BAR; CMP(0); BAR; STG(0, 10 * 32);
  VMW4; BAR; CMP(1); BAR; STG(1, 11 * 32);
  VMW4; BAR; CMP(0); BAR; STG(0, 12 * 32);
  VMW4; BAR; CMP(1); BAR; STG(1, 13 * 32);
  VMW4; BAR; CMP(0); BAR; STG(0, 14 * 32);
  VMW4; BAR; CMP(1); BAR; STG(1, 15 * 32);
  VMW4; BAR; CMP(0);
  VMW0; BAR; CMP(1);
#undef STG
#undef CMP

  int region = n0 >> 9;                       // 0=q,1=k,2=v (uniform per block)
  f16* dst = region == 0 ? qb : (region == 1 ? kb : vb);
  float scale = region == 0 ? 0.125f : 1.0f;
  int ncol0 = n0 - region * 512;
  float4 bias[4];
#pragma unroll
  for (int ni = 0; ni < 4; ni++)
    bias[ni] = *(const float4*)(bc + region * 512 + ncol0 + wc * 64 + ni * 16 +
                                hi * 4);
#pragma unroll
  for (int mi = 0; mi < 8; mi++) {
    int gr = m0 + wr * 128 + mi * 16 + lr;
    int b = gr >> 10, n = gr & 1023;
#pragma unroll
    for (int ni = 0; ni < 4; ni++) {
      int cc = ncol0 + wc * 64 + ni * 16 + hi * 4;
      int h = cc >> 6, d = cc & 63;
      f16x4 hv;
      hv[0] = (f16)((acc[ni][mi][0] + bias[ni].x) * scale);
      hv[1] = (f16)((acc[ni][mi][1] + bias[ni].y) * scale);
      hv[2] = (f16)((acc[ni][mi][2] + bias[ni].z) * scale);
      hv[3] = (f16)((acc[ni][mi][3] + bias[ni].w) * scale);
      *(f16x4*)(dst + (size_t)(((b * 8 + h) * 1024 + n) * 64 + d)) = hv;
    }
  }
}

// ---------------- K5: q_m/k_m = x_m @ Wq / Wkv_k (fp32, exact) ----------------
__global__ __launch_bounds__(512) void k_qmkm(
    const float* __restrict__ xm, const float* __restrict__ Wq,
    const float* __restrict__ Wkv, const float* __restrict__ bq,
    const float* __restrict__ bkv, float* __restrict__ qm,
    float* __restrict__ km) {
  __shared__ float xl[16][512];
  int bid = blockIdx.x;
  int b = bid >> 2, mg = bid & 3;
  int tid = threadIdx.x;
  for (int s = 0; s < 4; s++) {
    int idx = (tid + s * 512) * 4;
    int r = idx >> 9, cc = idx & 511;
    *(float4*)&xl[r][cc] =
        *(const float4*)(xm + (b * 64 + mg * 16 + r) * 512 + cc);
  }
  __syncthreads();
  int oc = tid;
  float aq[16] = {}, ak[16] = {};
  for (int cc = 0; cc < 512; cc += 4) {
    float wq0 = Wq[(cc + 0) * 512 + oc], wq1 = Wq[(cc + 1) * 512 + oc];
    float wq2 = Wq[(cc + 2) * 512 + oc], wq3 = Wq[(cc + 3) * 512 + oc];
    float wk0 = Wkv[(cc + 0) * 1024 + oc], wk1 = Wkv[(cc + 1) * 1024 + oc];
    float wk2 = Wkv[(cc + 2) * 1024 + oc], wk3 = Wkv[(cc + 3) * 1024 + oc];
    for (int mi = 0; mi < 16; mi++) {
      float4 xv = *(const float4*)&xl[mi][cc];
      aq[mi] += xv.x * wq0 + xv.y * wq1 + xv.z * wq2 + xv.w * wq3;
      ak[mi] += xv.x * wk0 + xv.y * wk1 + xv.z * wk2 + xv.w * wk3;
    }
  }
  int h = oc >> 6, d = oc & 63;
  for (int mi = 0; mi < 16; mi++) {
    int m = mg * 16 + mi;
    int base = ((b * 8 + h) * 64 + m) * 64 + d;
    qm[base] = (aq[mi] + bq[oc]) * 0.125f;
    km[base] = ak[mi] + bkv[oc];
  }
}

// ---------------- K6: temp = activ(qm @ km^T) fp32; row/col-sum maxes ----------------
__global__ __launch_bounds__(256) void k_temp(const float* __restrict__ qm,
                                              const float* __restrict__ km,
                                              float* __restrict__ temp,
                                              unsigned* __restrict__ den) {
  __shared__ float ql[64][68], kl[64][68];
  __shared__ float rs[64], cs[64];
  int g = blockIdx.x, tid = threadIdx.x;
  for (int idx = tid; idx < 4096; idx += 256) {
    int r = idx >> 6, c = idx & 63;
    ql[r][c] = qm[g * 4096 + idx];
    kl[r][c] = km[g * 4096 + idx];
  }
  __syncthreads();
  int ti = tid >> 4, tj = tid & 15;
  float acc[4][4] = {};
  for (int kk = 0; kk < 64; kk += 4) {
    float4 qa[4], kb[4];
    for (int i = 0; i < 4; i++) qa[i] = *(const float4*)&ql[ti * 4 + i][kk];
    for (int j = 0; j < 4; j++) kb[j] = *(const float4*)&kl[tj * 4 + j][kk];
    for (int i = 0; i < 4; i++)
      for (int j = 0; j < 4; j++)
        acc[i][j] += qa[i].x * kb[j].x + qa[i].y * kb[j].y +
                     qa[i].z * kb[j].z + qa[i].w * kb[j].w;
  }
  float e[4][4];
  for (int i = 0; i < 4; i++)
    for (int j = 0; j < 4; j++) {
      float xx = acc[i][j];
      e[i][j] = xx > 0.f ? 1.f + xx : __expf(xx);
    }
  __syncthreads();
  for (int i = 0; i < 4; i++)
    for (int j = 0; j < 4; j++) kl[ti * 4 + i][tj * 4 + j] = e[i][j];
  __syncthreads();
  for (int idx = tid; idx < 4096; idx += 256)
    temp[g * 4096 + idx] = kl[idx >> 6][idx & 63];
  if (tid < 64) {
    float s = 0.f;
    for (int j = 0; j < 64; j++) s += kl[tid][j];
    rs[tid] = s;
  } else if (tid < 128) {
    int c = tid - 64;
    float s = 0.f;
    for (int i = 0; i < 64; i++) s += kl[i][c];
    cs[c] = s;
  }
  __syncthreads();
  if (tid == 0) {
    float mx = rs[0];
    for (int i = 1; i < 64; i++) mx = fmaxf(mx, rs[i]);
    atomicMax(den + 0, __float_as_uint(mx));
  }
  if (tid == 1) {
    float mx = cs[0];
    for (int i = 1; i < 64; i++) mx = fmaxf(mx, cs[i]);
    atomicMax(den + 1, __float_as_uint(mx));
  }
}

// ---------------- K7: Newton-Schulz pinv (f16 MFMA with +1 offset split) ----------------
__global__ __launch_bounds__(256) void k_pinv(const float* __restrict__ temp,
                                              const unsigned* __restrict__ den,
                                              float* __restrict__ z) {
  __shared__ f16 wh[64][72], Zh[64][72], ZhT[64][72], GhT[64][72], W1h[64][72],
      W2h[64][72];
  __shared__ float colZ[64];
  int g = blockIdx.x, tid = threadIdx.x;
  float dn = __uint_as_float(den[0]) * __uint_as_float(den[1]);
  float inv = 1.0f / dn;
  for (int idx = tid; idx < 4096; idx += 256) {
    int r = idx >> 6, c = idx & 63;
    float t = temp[g * 4096 + idx];
    wh[r][c] = (f16)(t - 1.0f);
    ZhT[r][c] = (f16)(t * inv);
  }
  __syncthreads();
  for (int idx = tid; idx < 4096; idx += 256) {
    int r = idx >> 6, c = idx & 63;
    Zh[r][c] = ZhT[c][r];
  }
  __syncthreads();
  int lane = tid & 63, w = tid >> 6, lr = lane & 15, hi = lane >> 4;
  int rb = w * 16;
  for (int it = 0; it < 6; it++) {
    if (tid < 64) {
      float s = 0.f;
      for (int i = 0; i < 64; i++) s += (float)ZhT[tid][i];
      colZ[tid] = s;
    }
    __syncthreads();
    {  // G = w@Z + colZ -> GhT
      f32x4 acc[4] = {};
      for (int kc = 0; kc < 2; kc++) {
        f16x8 a = *(const f16x8*)&wh[rb + lr][kc * 32 + hi * 8];
        for (int cj = 0; cj < 4; cj++)
          acc[cj] = MFMA16(
              a, *(const f16x8*)&ZhT[cj * 16 + lr][kc * 32 + hi * 8], acc[cj]);
      }
      for (int cj = 0; cj < 4; cj++)
        for (int rg = 0; rg < 4; rg++) {
          int rr = rb + hi * 4 + rg, cc = cj * 16 + lr;
          GhT[cc][rr] = (f16)(acc[cj][rg] + colZ[cc]);
        }
    }
    __syncthreads();
    {  // W1 = Z@G
      f32x4 acc[4] = {};
      for (int kc = 0; kc < 2; kc++) {
        f16x8 a = *(const f16x8*)&Zh[rb + lr][kc * 32 + hi * 8];
        for (int cj = 0; cj < 4; cj++)
          acc[cj] = MFMA16(
              a, *(const f16x8*)&GhT[cj * 16 + lr][kc * 32 + hi * 8], acc[cj]);
      }
      for (int cj = 0; cj < 4; cj++)
        for (int rg = 0; rg < 4; rg++)
          W1h[rb + hi * 4 + rg][cj * 16 + lr] = (f16)acc[cj][rg];
    }
    __syncthreads();
    {  // W2 = W1@G
      f32x4 acc[4] = {};
      for (int kc = 0; kc < 2; kc++) {
        f16x8 a = *(const f16x8*)&W1h[rb + lr][kc * 32 + hi * 8];
        for (int cj = 0; cj < 4; cj++)
          acc[cj] = MFMA16(
              a, *(const f16x8*)&GhT[cj * 16 + lr][kc * 32 + hi * 8], acc[cj]);
      }
      for (int cj = 0; cj < 4; cj++)
        for (int rg = 0; rg < 4; rg++)
          W2h[rb + hi * 4 + rg][cj * 16 + lr] = (f16)acc[cj][rg];
    }
    __syncthreads();
    {  // W3 = W2@G ; Z' = 3.25Z - 3.75W1 + 1.75W2 - 0.25W3
      f32x4 acc[4] = {};
      for (int kc = 0; kc < 2; kc++) {
        f16x8 a = *(const f16x8*)&W2h[rb + lr][kc * 32 + hi * 8];
        for (int cj = 0; cj < 4; cj++)
          acc[cj] = MFMA16(
              a, *(const f16x8*)&GhT[cj * 16 + lr][kc * 32 + hi * 8], acc[cj]);
      }
      for (int cj = 0; cj < 4; cj++)
        for (int rg = 0; rg < 4; rg++) {
          int rr = rb + hi * 4 + rg, cc = cj * 16 + lr;
          float zn = 3.25f * (float)Zh[rr][cc] - 3.75f * (float)W1h[rr][cc] +
                     1.75f * (float)W2h[rr][cc] - 0.25f * acc[cj][rg];
          if (it == 5) {
            z[g * 4096 + rr * 64 + cc] = zn;
          } else {
            Zh[rr][cc] = (f16)zn;
            ZhT[cc][rr] = (f16)zn;
          }
        }
    }
    __syncthreads();
  }
}

// ---------------- K8: fused kqmkv + w2 + attn; prefetched K/V/Q pipelines ----------------
__global__ __launch_bounds__(256) void k_kwa(
    const float* __restrict__ qm, const f16* __restrict__ kb,
    const f16* __restrict__ vb, const float* __restrict__ zz,
    const float* __restrict__ km, const f16* __restrict__ qb,
    f16* __restrict__ attn) {
  __shared__ __align__(16) char smem[76288];
  int g = blockIdx.x, tid = threadIdx.x;
  int lane = tid & 63, w = tid >> 6, lr = lane & 15, hi = lane >> 4;
  int srow8 = tid >> 3;
  int cgs = (tid & 7) ^ (srow8 & 7);
  f16* klp = (f16*)(smem + 59904);  // [128][64] staged K (phase1) / Q (phase3)
  // ---- phase 1 regions: qh[0,9216) vt[9216,30976) Slk[30976,48384) w2l[48384,59904)
  f16(*qh)[72] = (f16(*)[72])smem;
  f16(*vt)[136] = (f16(*)[136])(smem + 9216);
  f16(*Slk)[136] = (f16(*)[136])(smem + 30976);
  f16(*w2l)[72] = (f16(*)[72])(smem + 48384);
  for (int idx = tid; idx < 4096; idx += 256) {
    int r = idx >> 6, c = idx & 63;
    qh[r][c] = (f16)qm[g * 4096 + idx];
  }
  for (int idx = tid; idx < 16 * 136; idx += 256) {
    int r = 64 + idx / 136, c = idx % 136;
    vt[r][c] = (r == 64) ? (f16)1.0f : (f16)0.0f;
  }
  f32x4 acc2[5] = {};
  const f16* kbase = kb + (size_t)g * 65536;
  const f16* vbase = vb + (size_t)g * 65536;
  int vrow = tid >> 3, vch = tid & 7;
  f16x8 vr0, vr1, vr2, vr3;
  // prologue: stage K chunk 0 + V chunk 0 into regs
#pragma unroll
  for (int s = 0; s < 4; s++)
    gload16(kbase + (size_t)(srow8 + s * 32) * 64 + cgs * 8,
            klp + tid * 8 + s * 2048);
  vr0 = *(const f16x8*)(vbase + (size_t)vrow * 64 + vch * 8);
  vr1 = *(const f16x8*)(vbase + (size_t)(vrow + 32) * 64 + vch * 8);
  vr2 = *(const f16x8*)(vbase + (size_t)(vrow + 64) * 64 + vch * 8);
  vr3 = *(const f16x8*)(vbase + (size_t)(vrow + 96) * 64 + vch * 8);
  for (int n0 = 0; n0 < 1024; n0 += 128) {
    __syncthreads();  // klp(n0) ready (vmcnt drain); vt free (prev PV done)
#pragma unroll
    for (int j = 0; j < 8; j++) vt[vch * 8 + j][vrow] = vr0[j];
#pragma unroll
    for (int j = 0; j < 8; j++) vt[vch * 8 + j][vrow + 32] = vr1[j];
#pragma unroll
    for (int j = 0; j < 8; j++) vt[vch * 8 + j][vrow + 64] = vr2[j];
#pragma unroll
    for (int j = 0; j < 8; j++) vt[vch * 8 + j][vrow + 96] = vr3[j];
    __syncthreads();  // vt visible
    f32x4 sacc[8] = {};
    for (int kc = 0; kc < 2; kc++) {
      f16x8 a = *(const f16x8*)&qh[w * 16 + lr][kc * 32 + hi * 8];
      for (int cj = 0; cj < 8; cj++)
        sacc[cj] = MFMA16(a, lds8(klp, cj * 16 + lr, kc * 4 + hi), sacc[cj]);
    }
    for (int cj = 0; cj < 8; cj++)
      for (int rg = 0; rg < 4; rg++) {
        float xx = sacc[cj][rg];
        Slk[w * 16 + hi * 4 + rg][cj * 16 + lr] =
            (f16)(xx > 0.f ? 1.f + xx : __expf(xx));
      }
    __syncthreads();  // Slk visible; all waves' klp reads complete
    if (n0 < 896) {   // prefetch next K chunk + V regs, hidden under PV
      int nn = n0 + 128;
#pragma unroll
      for (int s = 0; s < 4; s++)
        gload16(kbase + (size_t)(nn + srow8 + s * 32) * 64 + cgs * 8,
                klp + tid * 8 + s * 2048);
      vr0 = *(const f16x8*)(vbase + (size_t)(nn + vrow) * 64 + vch * 8);
      vr1 = *(const f16x8*)(vbase + (size_t)(nn + vrow + 32) * 64 + vch * 8);
      vr2 = *(const f16x8*)(vbase + (size_t)(nn + vrow + 64) * 64 + vch * 8);
      vr3 = *(const f16x8*)(vbase + (size_t)(nn + vrow + 96) * 64 + vch * 8);
    }
    for (int kc2 = 0; kc2 < 4; kc2++) {
      f16x8 a = *(const f16x8*)&Slk[w * 16 + lr][kc2 * 32 + hi * 8];
      for (int ce = 0; ce < 5; ce++)
        acc2[ce] = MFMA16(
            a, *(const f16x8*)&vt[ce * 16 + lr][kc2 * 32 + hi * 8], acc2[ce]);
    }
  }
  __syncthreads();  // all phase-1 LDS reads complete
  // ---- phase 2 regions: kql(f32)[0,21504) zl(f32)[30976,48384); w2l persists
  float(*kql)[84] = (float(*)[84])smem;
  float(*zl)[68] = (float(*)[68])(smem + 30976);
  for (int ce = 0; ce < 5; ce++)
    for (int rg = 0; rg < 4; rg++)
      kql[w * 16 + hi * 4 + rg][ce * 16 + lr] = acc2[ce][rg];
  for (int idx = tid; idx < 4096; idx += 256)
    zl[idx >> 6][idx & 63] = zz[g * 4096 + idx];
  __syncthreads();
  const f16* qgb = qb + (size_t)g * 65536;
  // prefetch Q chunk 0 into klp, hidden under the fp32 GEMM below
#pragma unroll
  for (int s = 0; s < 4; s++)
    gload16(qgb + (size_t)(srow8 + s * 32) * 64 + cgs * 8,
            klp + tid * 8 + s * 2048);
  {
    int ti = tid >> 4, tj = tid & 15;
    float acc[4][5] = {};
    for (int kk = 0; kk < 64; kk++) {
      float a0 = zl[ti * 4 + 0][kk], a1 = zl[ti * 4 + 1][kk];
      float a2 = zl[ti * 4 + 2][kk], a3 = zl[ti * 4 + 3][kk];
      for (int j = 0; j < 5; j++) {
        float bv = kql[kk][tj * 5 + j];
        acc[0][j] += a0 * bv; acc[1][j] += a1 * bv;
        acc[2][j] += a2 * bv; acc[3][j] += a3 * bv;
      }
    }
    for (int i = 0; i < 4; i++)
      for (int j = 0; j < 5; j++)
        w2l[tj * 5 + j][ti * 4 + i] = (f16)acc[i][j];
  }
  __syncthreads();  // kql/zl reads done; w2l visible; klp(Q0) drained
  // ---- phase 3 regions: kmh[0,9216) Sl[9216,27648); w2l persists; klp = Q stage
  f16(*kmh)[72] = (f16(*)[72])smem;
  f16(*Sl)[72] = (f16(*)[72])(smem + 9216);
  int b = g >> 3, h = g & 7;
  for (int idx = tid; idx < 4096; idx += 256)
    kmh[idx >> 6][idx & 63] = (f16)km[g * 4096 + idx];
  __syncthreads();  // kmh visible
  for (int nt = 0; nt < 8; nt++) {
    int n0 = nt * 128;
    f32x4 sacc[2][4] = {};
    for (int kc = 0; kc < 2; kc++)
      for (int ri = 0; ri < 2; ri++) {
        f16x8 a = lds8(klp, w * 32 + ri * 16 + lr, kc * 4 + hi);
        for (int cj = 0; cj < 4; cj++)
          sacc[ri][cj] = MFMA16(
              a, *(const f16x8*)&kmh[cj * 16 + lr][kc * 32 + hi * 8],
              sacc[ri][cj]);
      }
    for (int ri = 0; ri < 2; ri++)
      for (int cj = 0; cj < 4; cj++)
        for (int rg = 0; rg < 4; rg++) {
          float xx = sacc[ri][cj][rg];
          Sl[w * 32 + ri * 16 + hi * 4 + rg][cj * 16 + lr] =
              (f16)(xx > 0.f ? 1.f + xx : __expf(xx));
        }
    __syncthreads();  // Sl visible; klp reads complete
    if (nt < 7) {     // prefetch next Q chunk, hidden under PV + store
#pragma unroll
      for (int s = 0; s < 4; s++)
        gload16(qgb + (size_t)(n0 + 128 + srow8 + s * 32) * 64 + cgs * 8,
                klp + tid * 8 + s * 2048);
    }
    f32x4 accP[5][2] = {};
    for (int kc = 0; kc < 2; kc++)
      for (int ri = 0; ri < 2; ri++) {
        f16x8 bfrag =
            *(const f16x8*)&Sl[w * 32 + ri * 16 + lr][kc * 32 + hi * 8];
        for (int ce = 0; ce < 5; ce++)
          accP[ce][ri] = MFMA16(
              *(const f16x8*)&w2l[ce * 16 + lr][kc * 32 + hi * 8], bfrag,
              accP[ce][ri]);
      }
    for (int ri = 0; ri < 2; ri++) {
      float dv = __shfl(accP[4][ri][0], lr, 64);
      float rd = 1.0f / (dv + 1e-12f);
      int n = w * 32 + ri * 16 + lr;
      for (int ce = 0; ce < 4; ce++) {
        f16x4 hv;
        hv[0] = (f16)(accP[ce][ri][0] * rd);
        hv[1] = (f16)(accP[ce][ri][1] * rd);
        hv[2] = (f16)(accP[ce][ri][2] * rd);
        hv[3] = (f16)(accP[ce][ri][3] * rd);
        *(f16x4*)(attn + (size_t)(b * 1024 + n0 + n) * 512 + h * 64 +
                  ce * 16 + hi * 4) = hv;
      }
    }
    __syncthreads();  // klp(nt+1) drained + Sl free for next iteration
  }
}

// ---------------- K11: out = attn @ Wp + bp, 256x256, BK=32, 2 blocks/CU ----------------
__global__ __launch_bounds__(512) void k_out(const f16* __restrict__ ah,
                                             const f16* __restrict__ WpT,
                                             const float* __restrict__ bp,
                                             float* __restrict__ out) {
  __shared__ f16 Al[2][256 * 32];
  __shared__ f16 Bl[2][256 * 32];
  int bid = blockIdx.x;
  int swz = (bid & 7) * 64 + (bid >> 3);    // nwg=512
  int ct = swz & 1, rt = swz >> 1;
  int m0 = rt * 256, n0 = ct * 256;
  int tid = threadIdx.x, lane = tid & 63, w = tid >> 6;
  int lr = lane & 15, hi = lane >> 4;
  int wr = w >> 2, wc = w & 3;

  int srow = tid >> 2;
  int cg = (tid & 3) ^ ((srow >> 1) & 3);
  const f16* gA = ah + (size_t)(m0 + srow) * 512 + cg * 8;
  const f16* gB = WpT + (size_t)(n0 + srow) * 512 + cg * 8;

  f32x4 acc[4][8] = {};

#define STG(BUF, K0)                                              \
  {                                                               \
    gload16(gA + (K0), &Al[BUF][tid * 8]);                        \
    gload16(gA + (K0) + 128 * 512, &Al[BUF][tid * 8 + 4096]);     \
    gload16(gB + (K0), &Bl[BUF][tid * 8]);                        \
    gload16(gB + (K0) + 128 * 512, &Bl[BUF][tid * 8 + 4096]);     \
  }
#define CMP(BUF)                                                  \
  {                                                               \
    __builtin_amdgcn_s_setprio(1);                                \
    f16x8 af[4], bf[8];                                           \
    _Pragma("unroll") for (int ni = 0; ni < 4; ni++)              \
        af[ni] = lds32(&Bl[BUF][0], wc * 64 + ni * 16 + lr, hi);  \
    _Pragma("unroll") for (int mi = 0; mi < 8; mi++)              \
        bf[mi] = lds32(&Al[BUF][0], wr * 128 + mi * 16 + lr, hi); \
    _Pragma("unroll") for (int ni = 0; ni < 4; ni++)              \
        _Pragma("unroll") for (int mi = 0; mi < 8; mi++)          \
            acc[ni][mi] = MFMA16(af[ni], bf[mi], acc[ni][mi]);    \
    __builtin_amdgcn_s_setprio(0);                                \
  }

  STG(0, 0);
  STG(1, 32);
  VMW4; BAR; CMP(0); BAR; STG(0, 2 * 32);
  VMW4; BAR; CMP(1); BAR; STG(1, 3 * 32);
  VMW4; BAR; CMP(0); BAR; STG(0, 4 * 32);
  VMW4; BAR; CMP(1); BAR; STG(1, 5 * 32);
  VMW4; BAR; CMP(0); BAR; STG(0, 6 * 32);
  VMW4; BAR; CMP(1); BAR; STG(1, 7 * 32);
  VMW4; BAR; CMP(0); BAR; STG(0, 8 * 32);
  VMW4; BAR; CMP(1); BAR; STG(1, 9 * 32);
  VMW4; BAR; CMP(0); BAR; STG(0, 10 * 32);
  VMW4; BAR; CMP(1); BAR; STG(1, 11 * 32);
  VMW4; BAR; CMP(0); BAR; STG(0, 12 * 32);
  VMW4; BAR; CMP(1); BAR; STG(1, 13 * 32);
  VMW4; BAR; CMP(0); BAR; STG(0, 14 * 32);
  VMW4; BAR; CMP(1); BAR; STG(1, 15 * 32);
  VMW4; BAR; CMP(0);
  VMW0; BAR; CMP(1);
#undef STG
#undef CMP

  float4 bias[4];
#pragma unroll
  for (int ni = 0; ni < 4; ni++)
    bias[ni] = *(const float4*)(bp + n0 + wc * 64 + ni * 16 + hi * 4);
#pragma unroll
  for (int mi = 0; mi < 8; mi++) {
    int gr = m0 + wr * 128 + mi * 16 + lr;
#pragma unroll
    for (int ni = 0; ni < 4; ni++) {
      int gc = n0 + wc * 64 + ni * 16 + hi * 4;
      float4 v;
      v.x = acc[ni][mi][0] + bias[ni].x;
      v.y = acc[ni][mi][1] + bias[ni].y;
      v.z = acc[ni][mi][2] + bias[ni].z;
      v.w = acc[ni][mi][3] + bias[ni].w;
      *(float4*)(out + (size_t)gr * 512 + gc) = v;
    }
  }
}

extern "C" void kernel_launch(void* const* d_in, const int* in_sizes, int n_in,
                              void* d_out, int out_size, void* d_ws,
                              size_t ws_size, hipStream_t stream) {
  (void)in_sizes; (void)n_in; (void)out_size; (void)ws_size;
  const float* x = (const float*)d_in[0];
  const float* Wq = (const float*)d_in[1];
  const float* bq = (const float*)d_in[2];
  const float* Wkv = (const float*)d_in[3];
  const float* bkv = (const float*)d_in[4];
  const float* Wp = (const float*)d_in[5];
  const float* bp = (const float*)d_in[6];
  float* outp = (float*)d_out;

  char* ws = (char*)d_ws;
  size_t o = 0;
  auto take = [&](size_t bytes) {
    char* p = ws + o;
    o += (bytes + 255) & ~(size_t)255;
    return p;
  };
  f16* WcT = (f16*)take(1536 * 512 * 2);
  f16* WpT = (f16*)take(512 * 512 * 2);
  float* bc = (float*)take(1536 * 4);
  f16* xh = (f16*)take(67108864);
  f16* qb = (f16*)take(67108864);
  f16* kb = (f16*)take(67108864);
  f16* vb = (f16*)take(67108864);

  // small scratch lives in d_out (128 MB); all consumed before k_out writes it
  char* od = (char*)d_out;
  size_t s = 0;
  auto sub = [&](size_t bytes) {
    char* p = od + s;
    s += (bytes + 255) & ~(size_t)255;
    return p;
  };
  float* xm = (float*)sub(64 * 64 * 512 * 4);
  float* qm = (float*)sub(512 * 4096 * 4);
  float* km = (float*)sub(512 * 4096 * 4);
  float* temp = (float*)sub(512 * 4096 * 4);
  float* zz = (float*)sub(512 * 4096 * 4);
  unsigned* den = (unsigned*)sub(256);
  f16* attn = xh;  // overlay: xh dead after k_qkv; k_kwa writes attn here

  hipLaunchKernelGGL(k_prep, dim3(2560), dim3(256), 0, stream, x, Wq, Wkv, Wp,
                     bq, bkv, xh, xm, WcT, WpT, bc, den);
  hipLaunchKernelGGL(k_qkv, dim3(1536), dim3(512), 0, stream, xh, WcT, bc,
                     qb, kb, vb);
  hipLaunchKernelGGL(k_qmkm, dim3(256), dim3(512), 0, stream, xm, Wq, Wkv, bq,
                     bkv, qm, km);
  hipLaunchKernelGGL(k_temp, dim3(512), dim3(256), 0, stream, qm, km, temp,
                     den);
  hipLaunchKernelGGL(k_pinv, dim3(512), dim3(256), 0, stream, temp, den, zz);
  hipLaunchKernelGGL(k_kwa, dim3(512), dim3(256), 0, stream, qm, kb, vb, zz,
                     km, qb, attn);
  hipLaunchKernelGGL(k_out, dim3(512), dim3(512), 0, stream, attn, WpT, bp,
                     outp);
}

// Round 18
// 472.648 us; speedup vs baseline: 1.0285x; 1.0285x over previous
//
#include <hip/hip_runtime.h>

typedef _Float16 f16;
typedef _Float16 f16x4 __attribute__((ext_vector_type(4)));
typedef _Float16 f16x8 __attribute__((ext_vector_type(8)));
typedef float f32x4 __attribute__((ext_vector_type(4)));

#define MFMA16(a, b, c) __builtin_amdgcn_mfma_f32_16x16x32_f16((a), (b), (c), 0, 0, 0)

__device__ __forceinline__ void gload16(const void* g, void* l) {
  __builtin_amdgcn_global_load_lds(
      (const __attribute__((address_space(1))) void*)g,
      (__attribute__((address_space(3))) void*)l, 16, 0, 0);
}

// swizzled LDS fragment read: buf is [rows][64] f16 linear, ch in 0..7 (16B chunks)
__device__ __forceinline__ f16x8 lds8(const f16* buf, int row, int ch) {
  return *(const f16x8*)(buf + row * 64 + ((ch ^ (row & 7)) << 3));
}

#define VMW8 asm volatile("s_waitcnt vmcnt(8)" ::: "memory")
#define VMW0 asm volatile("s_waitcnt vmcnt(0)" ::: "memory")
#define BAR __builtin_amdgcn_s_barrier()

// Sizes: B=64, N=1024, C=512, H=8, D=64, M=64, BH=512. SCALE=0.125f.

// ---------------- K1: fused prep: x->f16 + pooling (bid<512), weights (else) ----------------
__global__ __launch_bounds__(256) void k_prep(
    const float* __restrict__ x, const float* __restrict__ Wq,
    const float* __restrict__ Wkv, const float* __restrict__ Wp,
    const float* __restrict__ bq, const float* __restrict__ bkv,
    f16* __restrict__ xh, float* __restrict__ xm, f16* __restrict__ WcT,
    f16* __restrict__ WpT, float* __restrict__ bc,
    unsigned* __restrict__ den) {
  __shared__ float pl[4][8][512];
  int bid = blockIdx.x;
  int tid = threadIdx.x;
  if (bid >= 512) {
    int b = bid - 512;
    if (b < 1536) {
      for (int kk = tid; kk < 512; kk += 256) {
        float w = (b < 512) ? Wq[kk * 512 + b] : Wkv[kk * 1024 + (b - 512)];
        WcT[b * 512 + kk] = (f16)w;
      }
      if (tid == 0) bc[b] = (b < 512) ? bq[b] : bkv[b - 512];
      if (b == 0 && tid == 1) { den[0] = 0u; den[1] = 0u; }
    } else {
      int pc = b - 1536;
      for (int kk = tid; kk < 512; kk += 256)
        WpT[pc * 512 + kk] = (f16)Wp[kk * 512 + pc];
    }
    return;
  }
  int b = bid >> 3, a = bid & 7;
  int tr = tid >> 6, cl = tid & 63;
  int c0 = cl * 8;
  float pacc[8][8];
#pragma unroll
  for (int i = 0; i < 8; i++)
#pragma unroll
    for (int j = 0; j < 8; j++) pacc[i][j] = 0.f;
#pragma unroll
  for (int j = 0; j < 32; j++) {
    int n = a * 128 + tr * 32 + j;
    const float* row = x + (size_t)(b * 1024 + n) * 512 + c0;
    float4 v0 = *(const float4*)row;
    float4 v1 = *(const float4*)(row + 4);
    f16x8 h;
    h[0] = (f16)v0.x; h[1] = (f16)v0.y; h[2] = (f16)v0.z; h[3] = (f16)v0.w;
    h[4] = (f16)v1.x; h[5] = (f16)v1.y; h[6] = (f16)v1.z; h[7] = (f16)v1.w;
    *(f16x8*)(xh + (size_t)(b * 1024 + n) * 512 + c0) = h;
    int cg = j >> 2;
    pacc[cg][0] += v0.x; pacc[cg][1] += v0.y; pacc[cg][2] += v0.z;
    pacc[cg][3] += v0.w; pacc[cg][4] += v1.x; pacc[cg][5] += v1.y;
    pacc[cg][6] += v1.z; pacc[cg][7] += v1.w;
  }
#pragma unroll
  for (int cg = 0; cg < 8; cg++) {
    *(float4*)&pl[tr][cg][c0] =
        make_float4(pacc[cg][0], pacc[cg][1], pacc[cg][2], pacc[cg][3]);
    *(float4*)&pl[tr][cg][c0 + 4] =
        make_float4(pacc[cg][4], pacc[cg][5], pacc[cg][6], pacc[cg][7]);
  }
  __syncthreads();
#pragma unroll
  for (int s = 0; s < 4; s++) {
    int o = tid + s * 256;
    int cg = o >> 7, c4 = (o & 127) << 2;
    float4 r0 = *(const float4*)&pl[0][cg][c4];
    float4 r1 = *(const float4*)&pl[1][cg][c4];
    float4 r2 = *(const float4*)&pl[2][cg][c4];
    float4 r3 = *(const float4*)&pl[3][cg][c4];
    float4 r;
    r.x = (r0.x + r1.x + r2.x + r3.x) * 0.0625f;
    r.y = (r0.y + r1.y + r2.y + r3.y) * 0.0625f;
    r.z = (r0.z + r1.z + r2.z + r3.z) * 0.0625f;
    r.w = (r0.w + r1.w + r2.w + r3.w) * 0.0625f;
    *(float4*)(xm + (size_t)(b * 64 + a * 8 + cg) * 512 + c4) = r;
  }
}

// ---------------- K3: QKV GEMM 256x256, counted-vmcnt pipeline (R9 exact) ----------------
__global__ __launch_bounds__(512) void k_qkv(
    const f16* __restrict__ xh, const f16* __restrict__ WcT,
    const float* __restrict__ bc, f16* __restrict__ qb, f16* __restrict__ kb,
    f16* __restrict__ vb) {
  __shared__ f16 Al[2][256 * 64];
  __shared__ f16 Bl[2][256 * 64];
  int bid = blockIdx.x;
  int swz = (bid & 7) * 192 + (bid >> 3);   // nwg=1536, bijective
  int ct = swz % 6, rt = swz / 6;
  int m0 = rt * 256, n0 = ct * 256;
  int tid = threadIdx.x, lane = tid & 63, w = tid >> 6;
  int lr = lane & 15, hi = lane >> 4;
  int wr = w >> 2, wc = w & 3;              // 2x4 wave grid; wave owns 128x64

  int srow = tid >> 3;
  int cg = (tid & 7) ^ (srow & 7);
  const f16* gA = xh + (size_t)(m0 + srow) * 512 + cg * 8;
  const f16* gB = WcT + (size_t)(n0 + srow) * 512 + cg * 8;

  f32x4 acc[4][8] = {};   // [ni][mi], swapped operands

#define STG(BUF, K0)                                                \
  {                                                                 \
    _Pragma("unroll") for (int s = 0; s < 4; s++) {                 \
      gload16(gA + (K0) + s * 64 * 512, &Al[BUF][tid * 8 + s * 4096]); \
      gload16(gB + (K0) + s * 64 * 512, &Bl[BUF][tid * 8 + s * 4096]); \
    }                                                               \
  }
#define CMP(BUF)                                                    \
  {                                                                 \
    __builtin_amdgcn_s_setprio(1);                                  \
    _Pragma("unroll") for (int kc = 0; kc < 2; kc++) {              \
      f16x8 af[4], bf[8];                                           \
      _Pragma("unroll") for (int ni = 0; ni < 4; ni++)              \
          af[ni] = lds8(&Bl[BUF][0], wc * 64 + ni * 16 + lr, kc * 4 + hi); \
      _Pragma("unroll") for (int mi = 0; mi < 8; mi++)              \
          bf[mi] = lds8(&Al[BUF][0], wr * 128 + mi * 16 + lr, kc * 4 + hi); \
      _Pragma("unroll") for (int ni = 0; ni < 4; ni++)              \
          _Pragma("unroll") for (int mi = 0; mi < 8; mi++)          \
              acc[ni][mi] = MFMA16(af[ni], bf[mi], acc[ni][mi]);    \
    }                                                               \
    __builtin_amdgcn_s_setprio(0);                                  \
  }

  STG(0, 0);
  STG(1, 64);
  VMW8; BAR; CMP(0); BAR; STG(0, 2 * 64);
  VMW8; BAR; CMP(1); BAR; STG(1, 3 * 64);
  VMW8; BAR; CMP(0); BAR; STG(0, 4 * 64);
  VMW8; BAR; CMP(1); BAR; STG(1, 5 * 64);
  VMW8; BAR; CMP(0); BAR; STG(0, 6 * 64);
  VMW8; BAR; CMP(1); BAR; STG(1, 7 * 64);
  VMW8; BAR; CMP(0);
  VMW0; BAR; CMP(1);
#undef STG
#undef CMP

  int region = n0 >> 9;                       // 0=q,1=k,2=v (uniform per block)
  f16* dst = region == 0 ? qb : (region == 1 ? kb : vb);
  float scale = region == 0 ? 0.125f : 1.0f;
  int ncol0 = n0 - region * 512;
  float4 bias[4];
#pragma unroll
  for (int ni = 0; ni < 4; ni++)
    bias[ni] = *(const float4*)(bc + region * 512 + ncol0 + wc * 64 + ni * 16 +
                                hi * 4);
#pragma unroll
  for (int mi = 0; mi < 8; mi++) {
    int gr = m0 + wr * 128 + mi * 16 + lr;
    int b = gr >> 10, n = gr & 1023;
#pragma unroll
    for (int ni = 0; ni < 4; ni++) {
      int cc = ncol0 + wc * 64 + ni * 16 + hi * 4;
      int h = cc >> 6, d = cc & 63;
      f16x4 hv;
      hv[0] = (f16)((acc[ni][mi][0] + bias[ni].x) * scale);
      hv[1] = (f16)((acc[ni][mi][1] + bias[ni].y) * scale);
      hv[2] = (f16)((acc[ni][mi][2] + bias[ni].z) * scale);
      hv[3] = (f16)((acc[ni][mi][3] + bias[ni].w) * scale);
      *(f16x4*)(dst + (size_t)(((b * 8 + h) * 1024 + n) * 64 + d)) = hv;
    }
  }
}

// ---------------- K5: q_m/k_m = x_m @ Wq / Wkv_k (fp32, exact) ----------------
__global__ __launch_bounds__(512) void k_qmkm(
    const float* __restrict__ xm, const float* __restrict__ Wq,
    const float* __restrict__ Wkv, const float* __restrict__ bq,
    const float* __restrict__ bkv, float* __restrict__ qm,
    float* __restrict__ km) {
  __shared__ float xl[16][512];
  int bid = blockIdx.x;
  int b = bid >> 2, mg = bid & 3;
  int tid = threadIdx.x;
  for (int s = 0; s < 4; s++) {
    int idx = (tid + s * 512) * 4;
    int r = idx >> 9, cc = idx & 511;
    *(float4*)&xl[r][cc] =
        *(const float4*)(xm + (b * 64 + mg * 16 + r) * 512 + cc);
  }
  __syncthreads();
  int oc = tid;
  float aq[16] = {}, ak[16] = {};
  for (int cc = 0; cc < 512; cc += 4) {
    float wq0 = Wq[(cc + 0) * 512 + oc], wq1 = Wq[(cc + 1) * 512 + oc];
    float wq2 = Wq[(cc + 2) * 512 + oc], wq3 = Wq[(cc + 3) * 512 + oc];
    float wk0 = Wkv[(cc + 0) * 1024 + oc], wk1 = Wkv[(cc + 1) * 1024 + oc];
    float wk2 = Wkv[(cc + 2) * 1024 + oc], wk3 = Wkv[(cc + 3) * 1024 + oc];
    for (int mi = 0; mi < 16; mi++) {
      float4 xv = *(const float4*)&xl[mi][cc];
      aq[mi] += xv.x * wq0 + xv.y * wq1 + xv.z * wq2 + xv.w * wq3;
      ak[mi] += xv.x * wk0 + xv.y * wk1 + xv.z * wk2 + xv.w * wk3;
    }
  }
  int h = oc >> 6, d = oc & 63;
  for (int mi = 0; mi < 16; mi++) {
    int m = mg * 16 + mi;
    int base = ((b * 8 + h) * 64 + m) * 64 + d;
    qm[base] = (aq[mi] + bq[oc]) * 0.125f;
    km[base] = ak[mi] + bkv[oc];
  }
}

// ---------------- K6: temp = activ(qm @ km^T) fp32; row/col-sum maxes ----------------
__global__ __launch_bounds__(256) void k_temp(const float* __restrict__ qm,
                                              const float* __restrict__ km,
                                              float* __restrict__ temp,
                                              unsigned* __restrict__ den) {
  __shared__ float ql[64][68], kl[64][68];
  __shared__ float rs[64], cs[64];
  int g = blockIdx.x, tid = threadIdx.x;
  for (int idx = tid; idx < 4096; idx += 256) {
    int r = idx >> 6, c = idx & 63;
    ql[r][c] = qm[g * 4096 + idx];
    kl[r][c] = km[g * 4096 + idx];
  }
  __syncthreads();
  int ti = tid >> 4, tj = tid & 15;
  float acc[4][4] = {};
  for (int kk = 0; kk < 64; kk += 4) {
    float4 qa[4], kb[4];
    for (int i = 0; i < 4; i++) qa[i] = *(const float4*)&ql[ti * 4 + i][kk];
    for (int j = 0; j < 4; j++) kb[j] = *(const float4*)&kl[tj * 4 + j][kk];
    for (int i = 0; i < 4; i++)
      for (int j = 0; j < 4; j++)
        acc[i][j] += qa[i].x * kb[j].x + qa[i].y * kb[j].y +
                     qa[i].z * kb[j].z + qa[i].w * kb[j].w;
  }
  float e[4][4];
  for (int i = 0; i < 4; i++)
    for (int j = 0; j < 4; j++) {
      float xx = acc[i][j];
      e[i][j] = xx > 0.f ? 1.f + xx : __expf(xx);
    }
  __syncthreads();
  for (int i = 0; i < 4; i++)
    for (int j = 0; j < 4; j++) kl[ti * 4 + i][tj * 4 + j] = e[i][j];
  __syncthreads();
  for (int idx = tid; idx < 4096; idx += 256)
    temp[g * 4096 + idx] = kl[idx >> 6][idx & 63];
  if (tid < 64) {
    float s = 0.f;
    for (int j = 0; j < 64; j++) s += kl[tid][j];
    rs[tid] = s;
  } else if (tid < 128) {
    int c = tid - 64;
    float s = 0.f;
    for (int i = 0; i < 64; i++) s += kl[i][c];
    cs[c] = s;
  }
  __syncthreads();
  if (tid == 0) {
    float mx = rs[0];
    for (int i = 1; i < 64; i++) mx = fmaxf(mx, rs[i]);
    atomicMax(den + 0, __float_as_uint(mx));
  }
  if (tid == 1) {
    float mx = cs[0];
    for (int i = 1; i < 64; i++) mx = fmaxf(mx, cs[i]);
    atomicMax(den + 1, __float_as_uint(mx));
  }
}

// ---------------- K7: Newton-Schulz pinv (f16 MFMA with +1 offset split) ----------------
__global__ __launch_bounds__(256) void k_pinv(const float* __restrict__ temp,
                                              const unsigned* __restrict__ den,
                                              float* __restrict__ z) {
  __shared__ f16 wh[64][72], Zh[64][72], ZhT[64][72], GhT[64][72], W1h[64][72],
      W2h[64][72];
  __shared__ float colZ[64];
  int g = blockIdx.x, tid = threadIdx.x;
  float dn = __uint_as_float(den[0]) * __uint_as_float(den[1]);
  float inv = 1.0f / dn;
  for (int idx = tid; idx < 4096; idx += 256) {
    int r = idx >> 6, c = idx & 63;
    float t = temp[g * 4096 + idx];
    wh[r][c] = (f16)(t - 1.0f);
    ZhT[r][c] = (f16)(t * inv);
  }
  __syncthreads();
  for (int idx = tid; idx < 4096; idx += 256) {
    int r = idx >> 6, c = idx & 63;
    Zh[r][c] = ZhT[c][r];
  }
  __syncthreads();
  int lane = tid & 63, w = tid >> 6, lr = lane & 15, hi = lane >> 4;
  int rb = w * 16;
  for (int it = 0; it < 6; it++) {
    if (tid < 64) {
      float s = 0.f;
      for (int i = 0; i < 64; i++) s += (float)ZhT[tid][i];
      colZ[tid] = s;
    }
    __syncthreads();
    {  // G = w@Z + colZ -> GhT
      f32x4 acc[4] = {};
      for (int kc = 0; kc < 2; kc++) {
        f16x8 a = *(const f16x8*)&wh[rb + lr][kc * 32 + hi * 8];
        for (int cj = 0; cj < 4; cj++)
          acc[cj] = MFMA16(
              a, *(const f16x8*)&ZhT[cj * 16 + lr][kc * 32 + hi * 8], acc[cj]);
      }
      for (int cj = 0; cj < 4; cj++)
        for (int rg = 0; rg < 4; rg++) {
          int rr = rb + hi * 4 + rg, cc = cj * 16 + lr;
          GhT[cc][rr] = (f16)(acc[cj][rg] + colZ[cc]);
        }
    }
    __syncthreads();
    {  // W1 = Z@G
      f32x4 acc[4] = {};
      for (int kc = 0; kc < 2; kc++) {
        f16x8 a = *(const f16x8*)&Zh[rb + lr][kc * 32 + hi * 8];
        for (int cj = 0; cj < 4; cj++)
          acc[cj] = MFMA16(
              a, *(const f16x8*)&GhT[cj * 16 + lr][kc * 32 + hi * 8], acc[cj]);
      }
      for (int cj = 0; cj < 4; cj++)
        for (int rg = 0; rg < 4; rg++)
          W1h[rb + hi * 4 + rg][cj * 16 + lr] = (f16)acc[cj][rg];
    }
    __syncthreads();
    {  // W2 = W1@G
      f32x4 acc[4] = {};
      for (int kc = 0; kc < 2; kc++) {
        f16x8 a = *(const f16x8*)&W1h[rb + lr][kc * 32 + hi * 8];
        for (int cj = 0; cj < 4; cj++)
          acc[cj] = MFMA16(
              a, *(const f16x8*)&GhT[cj * 16 + lr][kc * 32 + hi * 8], acc[cj]);
      }
      for (int cj = 0; cj < 4; cj++)
        for (int rg = 0; rg < 4; rg++)
          W2h[rb + hi * 4 + rg][cj * 16 + lr] = (f16)acc[cj][rg];
    }
    __syncthreads();
    {  // W3 = W2@G ; Z' = 3.25Z - 3.75W1 + 1.75W2 - 0.25W3
      f32x4 acc[4] = {};
      for (int kc = 0; kc < 2; kc++) {
        f16x8 a = *(const f16x8*)&W2h[rb + lr][kc * 32 + hi * 8];
        for (int cj = 0; cj < 4; cj++)
          acc[cj] = MFMA16(
              a, *(const f16x8*)&GhT[cj * 16 + lr][kc * 32 + hi * 8], acc[cj]);
      }
      for (int cj = 0; cj < 4; cj++)
        for (int rg = 0; rg < 4; rg++) {
          int rr = rb + hi * 4 + rg, cc = cj * 16 + lr;
          float zn = 3.25f * (float)Zh[rr][cc] - 3.75f * (float)W1h[rr][cc] +
                     1.75f * (float)W2h[rr][cc] - 0.25f * acc[cj][rg];
          if (it == 5) {
            z[g * 4096 + rr * 64 + cc] = zn;
          } else {
            Zh[rr][cc] = (f16)zn;
            ZhT[cc][rr] = (f16)zn;
          }
        }
    }
    __syncthreads();
  }
}

// ---------------- K8: fused kqmkv + w2 + attn; prefetched K/V/Q pipelines ----------------
__global__ __launch_bounds__(256) void k_kwa(
    const float* __restrict__ qm, const f16* __restrict__ kb,
    const f16* __restrict__ vb, const float* __restrict__ zz,
    const float* __restrict__ km, const f16* __restrict__ qb,
    f16* __restrict__ attn) {
  __shared__ __align__(16) char smem[76288];
  int g = blockIdx.x, tid = threadIdx.x;
  int lane = tid & 63, w = tid >> 6, lr = lane & 15, hi = lane >> 4;
  int srow8 = tid >> 3;
  int cgs = (tid & 7) ^ (srow8 & 7);
  f16* klp = (f16*)(smem + 59904);  // [128][64] staged K (phase1) / Q (phase3)
  // ---- phase 1 regions: qh[0,9216) vt[9216,30976) Slk[30976,48384) w2l[48384,59904)
  f16(*qh)[72] = (f16(*)[72])smem;
  f16(*vt)[136] = (f16(*)[136])(smem + 9216);
  f16(*Slk)[136] = (f16(*)[136])(smem + 30976);
  f16(*w2l)[72] = (f16(*)[72])(smem + 48384);
  for (int idx = tid; idx < 4096; idx += 256) {
    int r = idx >> 6, c = idx & 63;
    qh[r][c] = (f16)qm[g * 4096 + idx];
  }
  for (int idx = tid; idx < 16 * 136; idx += 256) {
    int r = 64 + idx / 136, c = idx % 136;
    vt[r][c] = (r == 64) ? (f16)1.0f : (f16)0.0f;
  }
  f32x4 acc2[5] = {};
  const f16* kbase = kb + (size_t)g * 65536;
  const f16* vbase = vb + (size_t)g * 65536;
  int vrow = tid >> 3, vch = tid & 7;
  f16x8 vr0, vr1, vr2, vr3;
  // prologue: stage K chunk 0 + V chunk 0 into regs
#pragma unroll
  for (int s = 0; s < 4; s++)
    gload16(kbase + (size_t)(srow8 + s * 32) * 64 + cgs * 8,
            klp + tid * 8 + s * 2048);
  vr0 = *(const f16x8*)(vbase + (size_t)vrow * 64 + vch * 8);
  vr1 = *(const f16x8*)(vbase + (size_t)(vrow + 32) * 64 + vch * 8);
  vr2 = *(const f16x8*)(vbase + (size_t)(vrow + 64) * 64 + vch * 8);
  vr3 = *(const f16x8*)(vbase + (size_t)(vrow + 96) * 64 + vch * 8);
  for (int n0 = 0; n0 < 1024; n0 += 128) {
    __syncthreads();  // klp(n0) ready (vmcnt drain); vt free (prev PV done)
#pragma unroll
    for (int j = 0; j < 8; j++) vt[vch * 8 + j][vrow] = vr0[j];
#pragma unroll
    for (int j = 0; j < 8; j++) vt[vch * 8 + j][vrow + 32] = vr1[j];
#pragma unroll
    for (int j = 0; j < 8; j++) vt[vch * 8 + j][vrow + 64] = vr2[j];
#pragma unroll
    for (int j = 0; j < 8; j++) vt[vch * 8 + j][vrow + 96] = vr3[j];
    __syncthreads();  // vt visible
    f32x4 sacc[8] = {};
    for (int kc = 0; kc < 2; kc++) {
      f16x8 a = *(const f16x8*)&qh[w * 16 + lr][kc * 32 + hi * 8];
      for (int cj = 0; cj < 8; cj++)
        sacc[cj] = MFMA16(a, lds8(klp, cj * 16 + lr, kc * 4 + hi), sacc[cj]);
    }
    for (int cj = 0; cj < 8; cj++)
      for (int rg = 0; rg < 4; rg++) {
        float xx = sacc[cj][rg];
        Slk[w * 16 + hi * 4 + rg][cj * 16 + lr] =
            (f16)(xx > 0.f ? 1.f + xx : __expf(xx));
      }
    __syncthreads();  // Slk visible; all waves' klp reads complete
    if (n0 < 896) {   // prefetch next K chunk + V regs, hidden under PV
      int nn = n0 + 128;
#pragma unroll
      for (int s = 0; s < 4; s++)
        gload16(kbase + (size_t)(nn + srow8 + s * 32) * 64 + cgs * 8,
                klp + tid * 8 + s * 2048);
      vr0 = *(const f16x8*)(vbase + (size_t)(nn + vrow) * 64 + vch * 8);
      vr1 = *(const f16x8*)(vbase + (size_t)(nn + vrow + 32) * 64 + vch * 8);
      vr2 = *(const f16x8*)(vbase + (size_t)(nn + vrow + 64) * 64 + vch * 8);
      vr3 = *(const f16x8*)(vbase + (size_t)(nn + vrow + 96) * 64 + vch * 8);
    }
    for (int kc2 = 0; kc2 < 4; kc2++) {
      f16x8 a = *(const f16x8*)&Slk[w * 16 + lr][kc2 * 32 + hi * 8];
      for (int ce = 0; ce < 5; ce++)
        acc2[ce] = MFMA16(
            a, *(const f16x8*)&vt[ce * 16 + lr][kc2 * 32 + hi * 8], acc2[ce]);
    }
  }
  __syncthreads();  // all phase-1 LDS reads complete
  // ---- phase 2 regions: kql(f32)[0,21504) zl(f32)[30976,48384); w2l persists
  float(*kql)[84] = (float(*)[84])smem;
  float(*zl)[68] = (float(*)[68])(smem + 30976);
  for (int ce = 0; ce < 5; ce++)
    for (int rg = 0; rg < 4; rg++)
      kql[w * 16 + hi * 4 + rg][ce * 16 + lr] = acc2[ce][rg];
  for (int idx = tid; idx < 4096; idx += 256)
    zl[idx >> 6][idx & 63] = zz[g * 4096 + idx];
  __syncthreads();
  const f16* qgb = qb + (size_t)g * 65536;
  // prefetch Q chunk 0 into klp, hidden under the fp32 GEMM below
#pragma unroll
  for (int s = 0; s < 4; s++)
    gload16(qgb + (size_t)(srow8 + s * 32) * 64 + cgs * 8,
            klp + tid * 8 + s * 2048);
  {
    int ti = tid >> 4, tj = tid & 15;
    float acc[4][5] = {};
    for (int kk = 0; kk < 64; kk++) {
      float a0 = zl[ti * 4 + 0][kk], a1 = zl[ti * 4 + 1][kk];
      float a2 = zl[ti * 4 + 2][kk], a3 = zl[ti * 4 + 3][kk];
      for (int j = 0; j < 5; j++) {
        float bv = kql[kk][tj * 5 + j];
        acc[0][j] += a0 * bv; acc[1][j] += a1 * bv;
        acc[2][j] += a2 * bv; acc[3][j] += a3 * bv;
      }
    }
    for (int i = 0; i < 4; i++)
      for (int j = 0; j < 5; j++)
        w2l[tj * 5 + j][ti * 4 + i] = (f16)acc[i][j];
  }
  __syncthreads();  // kql/zl reads done; w2l visible; klp(Q0) drained
  // ---- phase 3 regions: kmh[0,9216) Sl[9216,27648); w2l persists; klp = Q stage
  f16(*kmh)[72] = (f16(*)[72])smem;
  f16(*Sl)[72] = (f16(*)[72])(smem + 9216);
  int b = g >> 3, h = g & 7;
  for (int idx = tid; idx < 4096; idx += 256)
    kmh[idx >> 6][idx & 63] = (f16)km[g * 4096 + idx];
  __syncthreads();  // kmh visible
  for (int nt = 0; nt < 8; nt++) {
    int n0 = nt * 128;
    f32x4 sacc[2][4] = {};
    for (int kc = 0; kc < 2; kc++)
      for (int ri = 0; ri < 2; ri++) {
        f16x8 a = lds8(klp, w * 32 + ri * 16 + lr, kc * 4 + hi);
        for (int cj = 0; cj < 4; cj++)
          sacc[ri][cj] = MFMA16(
              a, *(const f16x8*)&kmh[cj * 16 + lr][kc * 32 + hi * 8],
              sacc[ri][cj]);
      }
    for (int ri = 0; ri < 2; ri++)
      for (int cj = 0; cj < 4; cj++)
        for (int rg = 0; rg < 4; rg++) {
          float xx = sacc[ri][cj][rg];
          Sl[w * 32 + ri * 16 + hi * 4 + rg][cj * 16 + lr] =
              (f16)(xx > 0.f ? 1.f + xx : __expf(xx));
        }
    __syncthreads();  // Sl visible; klp reads complete
    if (nt < 7) {     // prefetch next Q chunk, hidden under PV + store
#pragma unroll
      for (int s = 0; s < 4; s++)
        gload16(qgb + (size_t)(n0 + 128 + srow8 + s * 32) * 64 + cgs * 8,
                klp + tid * 8 + s * 2048);
    }
    f32x4 accP[5][2] = {};
    for (int kc = 0; kc < 2; kc++)
      for (int ri = 0; ri < 2; ri++) {
        f16x8 bfrag =
            *(const f16x8*)&Sl[w * 32 + ri * 16 + lr][kc * 32 + hi * 8];
        for (int ce = 0; ce < 5; ce++)
          accP[ce][ri] = MFMA16(
              *(const f16x8*)&w2l[ce * 16 + lr][kc * 32 + hi * 8], bfrag,
              accP[ce][ri]);
      }
    for (int ri = 0; ri < 2; ri++) {
      float dv = __shfl(accP[4][ri][0], lr, 64);
      float rd = 1.0f / (dv + 1e-12f);
      int n = w * 32 + ri * 16 + lr;
      for (int ce = 0; ce < 4; ce++) {
        f16x4 hv;
        hv[0] = (f16)(accP[ce][ri][0] * rd);
        hv[1] = (f16)(accP[ce][ri][1] * rd);
        hv[2] = (f16)(accP[ce][ri][2] * rd);
        hv[3] = (f16)(accP[ce][ri][3] * rd);
        *(f16x4*)(attn + (size_t)(b * 1024 + n0 + n) * 512 + h * 64 +
                  ce * 16 + hi * 4) = hv;
      }
    }
    __syncthreads();  // klp(nt+1) drained + Sl free for next iteration
  }
}

// ---------------- K11: out = attn @ Wp + bp, 256x256, counted-vmcnt (R9 exact) ----------------
__global__ __launch_bounds__(512) void k_out(const f16* __restrict__ ah,
                                             const f16* __restrict__ WpT,
                                             const float* __restrict__ bp,
                                             float* __restrict__ out) {
  __shared__ f16 Al[2][256 * 64];
  __shared__ f16 Bl[2][256 * 64];
  int bid = blockIdx.x;
  int swz = (bid & 7) * 64 + (bid >> 3);    // nwg=512
  int ct = swz & 1, rt = swz >> 1;
  int m0 = rt * 256, n0 = ct * 256;
  int tid = threadIdx.x, lane = tid & 63, w = tid >> 6;
  int lr = lane & 15, hi = lane >> 4;
  int wr = w >> 2, wc = w & 3;

  int srow = tid >> 3;
  int cg = (tid & 7) ^ (srow & 7);
  const f16* gA = ah + (size_t)(m0 + srow) * 512 + cg * 8;
  const f16* gB = WpT + (size_t)(n0 + srow) * 512 + cg * 8;

  f32x4 acc[4][8] = {};

#define STG(BUF, K0)                                                \
  {                                                                 \
    _Pragma("unroll") for (int s = 0; s < 4; s++) {                 \
      gload16(gA + (K0) + s * 64 * 512, &Al[BUF][tid * 8 + s * 4096]); \
      gload16(gB + (K0) + s * 64 * 512, &Bl[BUF][tid * 8 + s * 4096]); \
    }                                                               \
  }
#define CMP(BUF)                                                    \
  {                                                                 \
    __builtin_amdgcn_s_setprio(1);                                  \
    _Pragma("unroll") for (int kc = 0; kc < 2; kc++) {              \
      f16x8 af[4], bf[8];                                           \
      _Pragma("unroll") for (int ni = 0; ni < 4; ni++)              \
          af[ni] = lds8(&Bl[BUF][0], wc * 64 + ni * 16 + lr, kc * 4 + hi); \
      _Pragma("unroll") for (int mi = 0; mi < 8; mi++)              \
          bf[mi] = lds8(&Al[BUF][0], wr * 128 + mi * 16 + lr, kc * 4 + hi); \
      _Pragma("unroll") for (int ni = 0; ni < 4; ni++)              \
          _Pragma("unroll") for (int mi = 0; mi < 8; mi++)          \
              acc[ni][mi] = MFMA16(af[ni], bf[mi], acc[ni][mi]);    \
    }                                                               \
    __builtin_amdgcn_s_setprio(0);                                  \
  }

  STG(0, 0);
  STG(1, 64);
  VMW8; BAR; CMP(0); BAR; STG(0, 2 * 64);
  VMW8; BAR; CMP(1); BAR; STG(1, 3 * 64);
  VMW8; BAR; CMP(0); BAR; STG(0, 4 * 64);
  VMW8; BAR; CMP(1); BAR; STG(1, 5 * 64);
  VMW8; BAR; CMP(0); BAR; STG(0, 6 * 64);
  VMW8; BAR; CMP(1); BAR; STG(1, 7 * 64);
  VMW8; BAR; CMP(0);
  VMW0; BAR; CMP(1);
#undef STG
#undef CMP

  float4 bias[4];
#pragma unroll
  for (int ni = 0; ni < 4; ni++)
    bias[ni] = *(const float4*)(bp + n0 + wc * 64 + ni * 16 + hi * 4);
#pragma unroll
  for (int mi = 0; mi < 8; mi++) {
    int gr = m0 + wr * 128 + mi * 16 + lr;
#pragma unroll
    for (int ni = 0; ni < 4; ni++) {
      int gc = n0 + wc * 64 + ni * 16 + hi * 4;
      float4 v;
      v.x = acc[ni][mi][0] + bias[ni].x;
      v.y = acc[ni][mi][1] + bias[ni].y;
      v.z = acc[ni][mi][2] + bias[ni].z;
      v.w = acc[ni][mi][3] + bias[ni].w;
      *(float4*)(out + (size_t)gr * 512 + gc) = v;
    }
  }
}

extern "C" void kernel_launch(void* const* d_in, const int* in_sizes, int n_in,
                              void* d_out, int out_size, void* d_ws,
                              size_t ws_size, hipStream_t stream) {
  (void)in_sizes; (void)n_in; (void)out_size; (void)ws_size;
  const float* x = (const float*)d_in[0];
  const float* Wq = (const float*)d_in[1];
  const float* bq = (const float*)d_in[2];
  const float* Wkv = (const float*)d_in[3];
  const float* bkv = (const float*)d_in[4];
  const float* Wp = (const float*)d_in[5];
  const float* bp = (const float*)d_in[6];
  float* outp = (float*)d_out;

  char* ws = (char*)d_ws;
  size_t o = 0;
  auto take = [&](size_t bytes) {
    char* p = ws + o;
    o += (bytes + 255) & ~(size_t)255;
    return p;
  };
  f16* WcT = (f16*)take(1536 * 512 * 2);
  f16* WpT = (f16*)take(512 * 512 * 2);
  float* bc = (float*)take(1536 * 4);
  f16* xh = (f16*)take(67108864);
  f16* qb = (f16*)take(67108864);
  f16* kb = (f16*)take(67108864);
  f16* vb = (f16*)take(67108864);

  // small scratch lives in d_out (128 MB); all consumed before k_out writes it
  char* od = (char*)d_out;
  size_t s = 0;
  auto sub = [&](size_t bytes) {
    char* p = od + s;
    s += (bytes + 255) & ~(size_t)255;
    return p;
  };
  float* xm = (float*)sub(64 * 64 * 512 * 4);
  float* qm = (float*)sub(512 * 4096 * 4);
  float* km = (float*)sub(512 * 4096 * 4);
  float* temp = (float*)sub(512 * 4096 * 4);
  float* zz = (float*)sub(512 * 4096 * 4);
  unsigned* den = (unsigned*)sub(256);
  f16* attn = xh;  // overlay: xh dead after k_qkv; k_kwa writes attn here

  hipLaunchKernelGGL(k_prep, dim3(2560), dim3(256), 0, stream, x, Wq, Wkv, Wp,
                     bq, bkv, xh, xm, WcT, WpT, bc, den);
  hipLaunchKernelGGL(k_qkv, dim3(1536), dim3(512), 0, stream, xh, WcT, bc,
                     qb, kb, vb);
  hipLaunchKernelGGL(k_qmkm, dim3(256), dim3(512), 0, stream, xm, Wq, Wkv, bq,
                     bkv, qm, km);
  hipLaunchKernelGGL(k_temp, dim3(512), dim3(256), 0, stream, qm, km, temp,
                     den);
  hipLaunchKernelGGL(k_pinv, dim3(512), dim3(256), 0, stream, temp, den, zz);
  hipLaunchKernelGGL(k_kwa, dim3(512), dim3(256), 0, stream, qm, kb, vb, zz,
                     km, qb, attn);
  hipLaunchKernelGGL(k_out, dim3(512), dim3(512), 0, stream, attn, WpT, bp,
                     outp);
}